// Round 17
// baseline (114.060 us; speedup 1.0000x reference)
//
#include <hip/hip_runtime.h>
#include <hip/hip_bf16.h>
#include <stdint.h>

#define NB 256
#define LQ 128
#define LC 512
#define DIM 384
#define CBP 392     // bf16 tile pitch in shorts (784 B)

typedef __attribute__((ext_vector_type(8))) short short8;
typedef __attribute__((ext_vector_type(4))) float f4;
typedef __attribute__((ext_vector_type(2))) unsigned int u32x2;

__device__ __forceinline__ unsigned int pk2bf(float a, float b) {
  union { float f; uint32_t u; } x, y; x.f = a; y.f = b;
  uint32_t lo = (x.u + 0x7fffu + ((x.u >> 16) & 1u)) >> 16;
  uint32_t hi = (y.u + 0x7fffu + ((y.u >> 16) & 1u)) >> 16;
  return lo | (hi << 16);
}

__device__ __forceinline__ void spin_ge(int* p, int target) {
  while (__hip_atomic_load(p, __ATOMIC_ACQUIRE, __HIP_MEMORY_SCOPE_WORKGROUP) < target) {}
  __builtin_amdgcn_sched_barrier(0);
}

// Round-16 BUG: flag_add executed per-lane (x64 per wave) -> consumers released
// after ONE producer lane; ring read uninitialized (inf bf16 patterns).
// Fix: lane-0-guarded increment; lgkmcnt is per-wave so the pre-add wait
// still covers all 64 lanes' ds_writes.
__device__ __forceinline__ void flag_add(int* p, int lane) {
  asm volatile("s_waitcnt lgkmcnt(0)" ::: "memory");
  if (lane == 0)
    __hip_atomic_fetch_add(p, 1, __ATOMIC_RELEASE, __HIP_MEMORY_SCOPE_WORKGROUP);
}

// Load 4 rows (rb..rb+3) of `base` (row pitch DIM f32) into a register bank.
__device__ __forceinline__ void issue6(const float* base, int rb, int lane,
                                       bool hiHalf, int l31, f4 (&V)[4], f4 (&H)[2]) {
#pragma unroll
  for (int i = 0; i < 4; ++i)
    V[i] = *((const f4*)(base + (size_t)(rb + i) * DIM) + lane);
#pragma unroll
  for (int j = 0; j < 2; ++j)
    H[j] = *((const f4*)(base + (size_t)(rb + 2 * j + (hiHalf ? 1 : 0)) * DIM) + 64 + l31);
}

// Consume a bank: raw-bf16 pack -> dst rows lr0..lr0+3 (pitch CBP), sumsq off
// the load path, masked pooled partials, inv norms (lane 0).
__device__ __forceinline__ void consume6(f4 (&V)[4], f4 (&H)[2],
    unsigned short* dst, int lr0, float* invdst, const int* mk,
    int lane, bool hiHalf, int l31, f4& pA, f4& pB, float& cnt) {
  float ss[4];
#pragma unroll
  for (int i = 0; i < 4; ++i) {
    u32x2 w; w[0] = pk2bf(V[i].x, V[i].y); w[1] = pk2bf(V[i].z, V[i].w);
    *(u32x2*)(dst + (size_t)(lr0 + i) * CBP + 4 * lane) = w;
    ss[i] = V[i].x * V[i].x + V[i].y * V[i].y + V[i].z * V[i].z + V[i].w * V[i].w;
  }
#pragma unroll
  for (int j = 0; j < 2; ++j) {
    u32x2 w; w[0] = pk2bf(H[j].x, H[j].y); w[1] = pk2bf(H[j].z, H[j].w);
    *(u32x2*)(dst + (size_t)(lr0 + 2 * j + (hiHalf ? 1 : 0)) * CBP + 256 + 4 * l31) = w;
    const float td = H[j].x * H[j].x + H[j].y * H[j].y + H[j].z * H[j].z + H[j].w * H[j].w;
    if (hiHalf) ss[2 * j + 1] += td; else ss[2 * j] += td;
  }
#pragma unroll
  for (int o = 32; o; o >>= 1) {
#pragma unroll
    for (int i = 0; i < 4; ++i) ss[i] += __shfl_xor(ss[i], o);
  }
  float fm[4];
#pragma unroll
  for (int i = 0; i < 4; ++i) fm[i] = (float)mk[i];
#pragma unroll
  for (int i = 0; i < 4; ++i) { pA += V[i] * fm[i]; cnt += fm[i]; }
#pragma unroll
  for (int j = 0; j < 2; ++j) pB += H[j] * (hiHalf ? fm[2 * j + 1] : fm[2 * j]);
  if (lane == 0) {
#pragma unroll
    for (int i = 0; i < 4; ++i) invdst[i] = 1.0f / fmaxf(sqrtf(ss[i]), 1e-12f);
  }
}

// =============== fused single-pass, producer/consumer waves ==================
__global__ __launch_bounds__(512, 2)
void fused_pc(const float* __restrict__ qtok, const float* __restrict__ ctok,
              const int* __restrict__ qm, const int* __restrict__ cm,
              float* __restrict__ pooled, float* __restrict__ late) {
  __shared__ unsigned short s_q[LQ][CBP];      // 100352 B (epilogue: f32 arena)
  __shared__ unsigned short s_ring[2][32][CBP];// 50176 B
  __shared__ float s_qi[LQ];
  __shared__ float s_ci[2][32];
  __shared__ int s_qm[LQ];
  __shared__ int s_cm[LC];
  __shared__ float s_rmax[LQ];
  __shared__ float s_cnt[16];
  __shared__ float s_wsum[2];
  __shared__ int s_flag[4];                    // produced[0..1], consumed[2..3]

  const int b = blockIdx.x, tid = threadIdx.x;
  const int wave = tid >> 6, lane = tid & 63;
  const int rA = lane & 15, hi = lane >> 4;
  const bool hiHalf = lane >= 32;
  const int l31 = lane & 31;

  const float* qb = qtok + (size_t)b * LQ * DIM;
  const float* cb = ctok + (size_t)b * LC * DIM;

  s_cm[tid] = cm[b * LC + tid];
  if (tid < LQ) s_qm[tid] = qm[b * LQ + tid];
  if (tid < 4) s_flag[tid] = 0;
  __syncthreads();

  f4 v0[4], h0[2], v1[4], h1[2];
  f4 pqA = {0,0,0,0}, pqB = {0,0,0,0}, pcA = {0,0,0,0}, pcB = {0,0,0,0};
  float cq = 0.f, cc = 0.f;

  // ---------------- phase 1: q (barrier-free; each wave owns its rows) ------
  {
    const int r0 = wave * 4;
    issue6(qb, 0 * 32 + r0, lane, hiHalf, l31, v0, h0);
    issue6(qb, 1 * 32 + r0, lane, hiHalf, l31, v1, h1);
    consume6(v0, h0, &s_q[0][0], 0 * 32 + r0, &s_qi[0 * 32 + r0], s_qm + 0 * 32 + r0,
             lane, hiHalf, l31, pqA, pqB, cq);
    issue6(qb, 2 * 32 + r0, lane, hiHalf, l31, v0, h0);
    consume6(v1, h1, &s_q[0][0], 1 * 32 + r0, &s_qi[1 * 32 + r0], s_qm + 1 * 32 + r0,
             lane, hiHalf, l31, pqA, pqB, cq);
    issue6(qb, 3 * 32 + r0, lane, hiHalf, l31, v1, h1);
    consume6(v0, h0, &s_q[0][0], 2 * 32 + r0, &s_qi[2 * 32 + r0], s_qm + 2 * 32 + r0,
             lane, hiHalf, l31, pqA, pqB, cq);
    consume6(v1, h1, &s_q[0][0], 3 * 32 + r0, &s_qi[3 * 32 + r0], s_qm + 3 * 32 + r0,
             lane, hiHalf, l31, pqA, pqB, cq);
  }
  __syncthreads();  // s_q, s_qi visible; flags initialized

  // ---------------- phase 2 ----------------
  if (wave < 4) {
    // ---- producer: stream 16 c tiles (8 rows/tile) through the 2-slot ring
    const int pr = wave * 8;
    issue6(cb, 0 * 32 + pr, lane, hiHalf, l31, v0, h0);        // tile 0 sub 0
    for (int t = 0; t < 16; ++t) {
      const int s = t & 1;
      issue6(cb, t * 32 + pr + 4, lane, hiHalf, l31, v1, h1);  // tile t sub 1
      if (t >= 2) spin_ge(&s_flag[2 + s], (t >> 1) * 4);       // slot free
      consume6(v0, h0, &s_ring[s][0][0], pr, &s_ci[s][pr], s_cm + t * 32 + pr,
               lane, hiHalf, l31, pcA, pcB, cc);
      if (t < 15) issue6(cb, (t + 1) * 32 + pr, lane, hiHalf, l31, v0, h0);
      consume6(v1, h1, &s_ring[s][0][0], pr + 4, &s_ci[s][pr + 4], s_cm + t * 32 + pr + 4,
               lane, hiHalf, l31, pcA, pcB, cc);
      flag_add(&s_flag[s], lane);   // wave-level: +1 per wave per tile
    }
  } else {
    // ---- consumer: q rows [w*32, w*32+32) vs every tile
    const int w = wave - 4;
    f4 rm0 = {-1e9f,-1e9f,-1e9f,-1e9f}, rm1 = {-1e9f,-1e9f,-1e9f,-1e9f};
    for (int t = 0; t < 16; ++t) {
      const int s = t & 1;
      spin_ge(&s_flag[s], ((t >> 1) + 1) * 4);  // all 4 producers done
      f4 a00 = {0,0,0,0}, a01 = {0,0,0,0}, a10 = {0,0,0,0}, a11 = {0,0,0,0};
#pragma unroll
      for (int kk = 0; kk < 12; ++kk) {
        const short8 b0 = *(const short8*)&s_ring[s][rA][kk * 32 + hi * 8];
        const short8 b1 = *(const short8*)&s_ring[s][rA + 16][kk * 32 + hi * 8];
        const short8 aA = *(const short8*)&s_q[w * 32 + rA][kk * 32 + hi * 8];
        const short8 aB = *(const short8*)&s_q[w * 32 + 16 + rA][kk * 32 + hi * 8];
        a00 = __builtin_amdgcn_mfma_f32_16x16x32_bf16(aA, b0, a00, 0, 0, 0);
        a01 = __builtin_amdgcn_mfma_f32_16x16x32_bf16(aA, b1, a01, 0, 0, 0);
        a10 = __builtin_amdgcn_mfma_f32_16x16x32_bf16(aB, b0, a10, 0, 0, 0);
        a11 = __builtin_amdgcn_mfma_f32_16x16x32_bf16(aB, b1, a11, 0, 0, 0);
      }
      const bool m0 = s_cm[t * 32 + rA] != 0;
      const bool m1 = s_cm[t * 32 + 16 + rA] != 0;
      const float ci0 = s_ci[s][rA], ci1 = s_ci[s][16 + rA];
#pragma unroll
      for (int r = 0; r < 4; ++r) {
        const float qi0 = s_qi[w * 32 + hi * 4 + r];
        const float qi1 = s_qi[w * 32 + 16 + hi * 4 + r];
        const float x00 = m0 ? a00[r] * (qi0 * ci0) : -1e9f;
        const float x01 = m1 ? a01[r] * (qi0 * ci1) : -1e9f;
        const float x10 = m0 ? a10[r] * (qi1 * ci0) : -1e9f;
        const float x11 = m1 ? a11[r] * (qi1 * ci1) : -1e9f;
        rm0[r] = fmaxf(rm0[r], fmaxf(x00, x01));
        rm1[r] = fmaxf(rm1[r], fmaxf(x10, x11));
      }
      flag_add(&s_flag[2 + s], lane);  // wave-level consumed mark
    }
    // reduce over the 16 col-class lanes; publish per-row maxes
#pragma unroll
    for (int r = 0; r < 4; ++r) {
#pragma unroll
      for (int o = 1; o < 16; o <<= 1) {
        rm0[r] = fmaxf(rm0[r], __shfl_xor(rm0[r], o));
        rm1[r] = fmaxf(rm1[r], __shfl_xor(rm1[r], o));
      }
    }
    if (rA == 0) {
#pragma unroll
      for (int r = 0; r < 4; ++r) {
        s_rmax[w * 32 + hi * 4 + r] = rm0[r];
        s_rmax[w * 32 + 16 + hi * 4 + r] = rm1[r];
      }
    }
  }
  __syncthreads();  // all tiles done; s_rmax ready; s_q free for arena reuse

  // ---------------- epilogue (r9-proven) ----------------
  float* red = (float*)&s_q[0][0];  // [8 waves][2 (q,c)][512] f32 = 32 KB
  *(f4*)&red[(wave * 2 + 0) * 512 + 4 * lane] = pqA;
  *(f4*)&red[(wave * 2 + 0) * 512 + 256 + (hiHalf ? 128 : 0) + 4 * l31] = pqB;
  *(f4*)&red[(wave * 2 + 1) * 512 + 4 * lane] = pcA;
  *(f4*)&red[(wave * 2 + 1) * 512 + 256 + (hiHalf ? 128 : 0) + 4 * l31] = pcB;
  if (lane == 0) { s_cnt[wave] = cq; s_cnt[8 + wave] = cc; }

  if (tid < LQ) {
    float ps = s_qm[tid] ? s_rmax[tid] : 0.f;
#pragma unroll
    for (int o = 32; o; o >>= 1) ps += __shfl_xor(ps, o);
    if ((tid & 63) == 0) s_wsum[tid >> 6] = ps;
  }
  __syncthreads();

  if (tid < DIM) {
    float sq = 0.f, sc = 0.f, nq = 0.f, nc = 0.f;
    if (tid < 256) {
#pragma unroll
      for (int w = 0; w < 8; ++w) {
        sq += red[(w * 2 + 0) * 512 + tid];
        sc += red[(w * 2 + 1) * 512 + tid];
      }
    } else {
#pragma unroll
      for (int w = 0; w < 8; ++w) {
        sq += red[(w * 2 + 0) * 512 + tid] + red[(w * 2 + 0) * 512 + tid + 128];
        sc += red[(w * 2 + 1) * 512 + tid] + red[(w * 2 + 1) * 512 + tid + 128];
      }
    }
#pragma unroll
    for (int w = 0; w < 8; ++w) { nq += s_cnt[w]; nc += s_cnt[8 + w]; }
    pooled[b * DIM + tid] = sq / fmaxf(nq, 1e-9f);
    pooled[(NB + b) * DIM + tid] = sc / fmaxf(nc, 1e-9f);
  }
  if (tid == 0) late[b] = s_wsum[0] + s_wsum[1];
}

// ================= tail kernels: round-1/9 proven shapes =====================
__global__ __launch_bounds__(DIM)
void mlp_v1(const float* __restrict__ pooled,
            const float* __restrict__ W1, const float* __restrict__ b1,
            const float* __restrict__ W2, const float* __restrict__ b2,
            float* __restrict__ emb) {
  __shared__ float s_in[DIM];
  __shared__ float s_h[DIM];
  __shared__ float s_red[6];
  const int row = blockIdx.y * NB + blockIdx.x;
  const int d = threadIdx.x;
  s_in[d] = pooled[(size_t)row * DIM + d];
  __syncthreads();
  float acc = b1[d];
#pragma unroll 8
  for (int k = 0; k < DIM; ++k) acc = fmaf(s_in[k], W1[k * DIM + d], acc);
  s_h[d] = fmaxf(acc, 0.f);
  __syncthreads();
  float p = b2[d];
#pragma unroll 8
  for (int k = 0; k < DIM; ++k) p = fmaf(s_h[k], W2[k * DIM + d], p);
  float ss = p * p;
#pragma unroll
  for (int o = 32; o; o >>= 1) ss += __shfl_xor(ss, o);
  if ((d & 63) == 0) s_red[d >> 6] = ss;
  __syncthreads();
  float tot = 0.f;
#pragma unroll
  for (int w = 0; w < 6; ++w) tot += s_red[w];
  emb[(size_t)row * DIM + d] = p * (1.0f / fmaxf(sqrtf(tot), 1e-12f));
}

__global__ __launch_bounds__(NB)
void contrast_kernel(const float* __restrict__ emb, float* __restrict__ out0) {
  __shared__ float s_q[DIM];
  const int i = blockIdx.x;
  for (int k = threadIdx.x; k < DIM; k += NB) s_q[k] = emb[(size_t)i * DIM + k];
  __syncthreads();
  const float* ce = emb + (size_t)(NB + threadIdx.x) * DIM;
  float acc = 0.f;
#pragma unroll 8
  for (int k = 0; k < DIM; ++k) acc = fmaf(s_q[k], ce[k], acc);
  out0[(size_t)i * NB + threadIdx.x] = acc / 0.07f;
}

// ============================== launch =======================================
extern "C" void kernel_launch(void* const* d_in, const int* in_sizes, int n_in,
                              void* d_out, int out_size, void* d_ws, size_t ws_size,
                              hipStream_t stream) {
  const float* qtok = (const float*)d_in[0];
  const float* ctok = (const float*)d_in[1];
  const int*   qmm  = (const int*)d_in[2];
  const int*   cmm  = (const int*)d_in[3];
  const float* W1   = (const float*)d_in[4];
  const float* b1   = (const float*)d_in[5];
  const float* W2   = (const float*)d_in[6];
  const float* b2   = (const float*)d_in[7];

  float* out0 = (float*)d_out;            // [NB*NB]
  float* late = out0 + NB * NB;           // [NB]
  float* pooled = (float*)d_ws;           // [2*NB][DIM]
  float* emb    = pooled + 2 * NB * DIM;  // [2*NB][DIM]

  hipLaunchKernelGGL(fused_pc, dim3(NB), dim3(512), 0, stream,
                     qtok, ctok, qmm, cmm, pooled, late);
  hipLaunchKernelGGL(mlp_v1, dim3(NB, 2), dim3(DIM), 0, stream,
                     pooled, W1, b1, W2, b2, emb);
  hipLaunchKernelGGL(contrast_kernel, dim3(NB), dim3(NB), 0, stream, emb, out0);
}

// Round 18
// 108.306 us; speedup vs baseline: 1.0531x; 1.0531x over previous
//
#include <hip/hip_runtime.h>
#include <hip/hip_bf16.h>
#include <stdint.h>

#define NB 256
#define LQ 128
#define LC 512
#define DIM 384
#define CBP 392     // bf16 tile pitch in shorts (784 B)
#define NST 20      // 4 q tiles + 16 c tiles, 32 rows each

typedef __attribute__((ext_vector_type(8))) short short8;
typedef __attribute__((ext_vector_type(4))) float f4;
typedef __attribute__((ext_vector_type(2))) unsigned int u32x2;

__device__ __forceinline__ unsigned int pk2bf(float a, float b) {
  union { float f; uint32_t u; } x, y; x.f = a; y.f = b;
  uint32_t lo = (x.u + 0x7fffu + ((x.u >> 16) & 1u)) >> 16;
  uint32_t hi = (y.u + 0x7fffu + ((y.u >> 16) & 1u)) >> 16;
  return lo | (hi << 16);
}

// ============== fused single-pass with per-block tile rotation ===============
// Measured-best configuration (round 15: 108.1 us total). r9 machinery:
// 2-deep register prefetch (12 f4/lane outstanding), counted vmcnt(6) never 0
// mid-loop, one barrier/stage, raw-bf16 MFMA with qi*ci recovered at the
// max-fold. Per-block tile rotation (q start b&3, c start b&15) is
// order-independent for max/sum and cost-neutral.
__global__ __launch_bounds__(512, 2)
void fused2r(const float* __restrict__ qtok, const float* __restrict__ ctok,
             const int* __restrict__ qm, const int* __restrict__ cm,
             float* __restrict__ pooled, float* __restrict__ late) {
  __shared__ unsigned short s_cb[2][32][CBP];  // 50176 B (epilogue: f32 arena)
  __shared__ float s_qi[LQ];
  __shared__ float s_ci[2][32];
  __shared__ int s_qm[LQ];
  __shared__ int s_cm[LC];
  __shared__ float s_cnt[16];
  __shared__ float s_wsum[8];

  const int b = blockIdx.x, tid = threadIdx.x;
  const int wave = tid >> 6, lane = tid & 63;
  const int rA = lane & 15, hi = lane >> 4;
  const bool hiHalf = lane >= 32;
  const int l31 = lane & 31;
  const int rq = b & 3, rc = b & 15;   // per-block rotations

  const float* qb = qtok + (size_t)b * LQ * DIM;
  const float* cb = ctok + (size_t)b * LC * DIM;

  s_cm[tid] = cm[b * LC + tid];
  if (tid < LQ) s_qm[tid] = qm[b * LQ + tid];
  __syncthreads();

  f4 v0[4], h0[2], v1[4], h1[2];
  f4 pqA = {0,0,0,0}, pqB = {0,0,0,0}, pcA = {0,0,0,0}, pcB = {0,0,0,0};
  float cq = 0.f, cc = 0.f;
  float rm[4] = {-1e9f, -1e9f, -1e9f, -1e9f};
  short8 A[12] = {};

#define TBASE(t) (((t) < 4) ? (qb + (size_t)((((t) + rq) & 3)) * 32 * DIM) \
                            : (cb + (size_t)((((t) - 4 + rc) & 15)) * 32 * DIM))

#define ISSUE(V, H, base_) do {                                              \
    const float* bb_ = (base_);                                              \
    _Pragma("unroll")                                                        \
    for (int i_ = 0; i_ < 4; ++i_)                                           \
      V[i_] = *((const f4*)(bb_ + (size_t)(wave * 4 + i_) * DIM) + lane);    \
    _Pragma("unroll")                                                        \
    for (int j_ = 0; j_ < 2; ++j_)                                           \
      H[j_] = *((const f4*)(bb_ + (size_t)(wave * 4 + 2 * j_ +               \
                (hiHalf ? 1 : 0)) * DIM) + 64 + l31);                        \
  } while (0)

#define STAGE(T, V, H, BUF) do {                                             \
    const int t_ = (T);                                                      \
    if (t_ == NST - 1) { asm volatile("s_waitcnt vmcnt(0)" ::: "memory"); }  \
    else               { asm volatile("s_waitcnt vmcnt(6)" ::: "memory"); }  \
    __builtin_amdgcn_sched_barrier(0);                                       \
    const bool isq_ = t_ < 4;                                                \
    const int rt_ = isq_ ? ((t_ + rq) & 3) : ((t_ - 4 + rc) & 15);           \
    const int* mk_ = isq_ ? (s_qm + rt_ * 32) : (s_cm + rt_ * 32);           \
    float ss_[4];                                                            \
    _Pragma("unroll")                                                        \
    for (int i_ = 0; i_ < 4; ++i_) {                                         \
      const int lr_ = wave * 4 + i_;                                         \
      u32x2 w_; w_[0] = pk2bf(V[i_].x, V[i_].y); w_[1] = pk2bf(V[i_].z, V[i_].w); \
      *(u32x2*)&s_cb[BUF][lr_][4 * lane] = w_;                               \
      ss_[i_] = V[i_].x * V[i_].x + V[i_].y * V[i_].y                        \
              + V[i_].z * V[i_].z + V[i_].w * V[i_].w;                       \
    }                                                                        \
    _Pragma("unroll")                                                        \
    for (int j_ = 0; j_ < 2; ++j_) {                                         \
      const int lr_ = wave * 4 + 2 * j_ + (hiHalf ? 1 : 0);                  \
      u32x2 w_; w_[0] = pk2bf(H[j_].x, H[j_].y); w_[1] = pk2bf(H[j_].z, H[j_].w); \
      *(u32x2*)&s_cb[BUF][lr_][256 + 4 * l31] = w_;                          \
      const float td_ = H[j_].x * H[j_].x + H[j_].y * H[j_].y               \
                      + H[j_].z * H[j_].z + H[j_].w * H[j_].w;              \
      if (hiHalf) ss_[2 * j_ + 1] += td_; else ss_[2 * j_] += td_;           \
    }                                                                        \
    _Pragma("unroll")                                                        \
    for (int o_ = 32; o_; o_ >>= 1) {                                        \
      _Pragma("unroll")                                                      \
      for (int i_ = 0; i_ < 4; ++i_) ss_[i_] += __shfl_xor(ss_[i_], o_);     \
    }                                                                        \
    float fm_[4];                                                            \
    _Pragma("unroll")                                                        \
    for (int i_ = 0; i_ < 4; ++i_) fm_[i_] = (float)mk_[wave * 4 + i_];      \
    if (isq_) {                                                              \
      _Pragma("unroll")                                                      \
      for (int i_ = 0; i_ < 4; ++i_) { pqA += V[i_] * fm_[i_]; cq += fm_[i_]; } \
      _Pragma("unroll")                                                      \
      for (int j_ = 0; j_ < 2; ++j_)                                         \
        pqB += H[j_] * (hiHalf ? fm_[2 * j_ + 1] : fm_[2 * j_]);             \
      if (lane == 0) {                                                       \
        _Pragma("unroll")                                                    \
        for (int i_ = 0; i_ < 4; ++i_)                                       \
          s_qi[rt_ * 32 + wave * 4 + i_] = 1.0f / fmaxf(sqrtf(ss_[i_]), 1e-12f); \
      }                                                                      \
    } else {                                                                 \
      _Pragma("unroll")                                                      \
      for (int i_ = 0; i_ < 4; ++i_) { pcA += V[i_] * fm_[i_]; cc += fm_[i_]; } \
      _Pragma("unroll")                                                      \
      for (int j_ = 0; j_ < 2; ++j_)                                         \
        pcB += H[j_] * (hiHalf ? fm_[2 * j_ + 1] : fm_[2 * j_]);             \
      if (lane == 0) {                                                       \
        _Pragma("unroll")                                                    \
        for (int i_ = 0; i_ < 4; ++i_)                                       \
          s_ci[BUF][wave * 4 + i_] = 1.0f / fmaxf(sqrtf(ss_[i_]), 1e-12f);   \
      }                                                                      \
    }                                                                        \
    if (t_ + 2 < NST) { ISSUE(V, H, TBASE(t_ + 2)); }                        \
    asm volatile("s_waitcnt lgkmcnt(0)" ::: "memory");                       \
    __builtin_amdgcn_s_barrier();                                            \
    __builtin_amdgcn_sched_barrier(0);                                       \
    if (isq_) {                                                              \
      if ((wave >> 1) == rt_) {  /* wave pair owns q rows [32*rt, +32) */    \
        const int lb_ = (wave & 1) * 16 + rA;                                \
        _Pragma("unroll")                                                    \
        for (int kk_ = 0; kk_ < 12; ++kk_)                                   \
          A[kk_] = *(const short8*)&s_cb[BUF][lb_][kk_ * 32 + hi * 8];       \
        asm volatile("s_waitcnt lgkmcnt(0)" ::: "memory");                   \
        __builtin_amdgcn_sched_barrier(0);                                   \
      }                                                                      \
    } else {                                                                 \
      f4 a0_ = {0,0,0,0}, a1_ = {0,0,0,0};                                   \
      _Pragma("unroll")                                                      \
      for (int kk_ = 0; kk_ < 12; ++kk_) {                                   \
        const short8 b0_ = *(const short8*)&s_cb[BUF][rA][kk_ * 32 + hi * 8];     \
        const short8 b1_ = *(const short8*)&s_cb[BUF][rA + 16][kk_ * 32 + hi * 8];\
        a0_ = __builtin_amdgcn_mfma_f32_16x16x32_bf16(A[kk_], b0_, a0_, 0, 0, 0); \
        a1_ = __builtin_amdgcn_mfma_f32_16x16x32_bf16(A[kk_], b1_, a1_, 0, 0, 0); \
      }                                                                      \
      const int tb_ = rt_ * 32;                                              \
      const bool m0_ = s_cm[tb_ + rA] != 0;                                  \
      const bool m1_ = s_cm[tb_ + rA + 16] != 0;                             \
      const float ci0_ = s_ci[BUF][rA], ci1_ = s_ci[BUF][rA + 16];           \
      _Pragma("unroll")                                                      \
      for (int r_ = 0; r_ < 4; ++r_) {                                       \
        const float qi_ = s_qi[wave * 16 + hi * 4 + r_];                     \
        const float x0_ = m0_ ? a0_[r_] * (qi_ * ci0_) : -1e9f;              \
        const float x1_ = m1_ ? a1_[r_] * (qi_ * ci1_) : -1e9f;              \
        rm[r_] = fmaxf(rm[r_], fmaxf(x0_, x1_));                             \
      }                                                                      \
    }                                                                        \
  } while (0)

  // prologue: banks for tiles 0 and 1 in flight
  ISSUE(v0, h0, TBASE(0));
  ISSUE(v1, h1, TBASE(1));

  for (int t = 0; t < NST; t += 2) {
    STAGE(t, v0, h0, 0);
    STAGE(t + 1, v1, h1, 1);
  }

  // ---------------- epilogue ----------------
#pragma unroll
  for (int r = 0; r < 4; ++r) {
#pragma unroll
    for (int o = 1; o < 16; o <<= 1) rm[r] = fmaxf(rm[r], __shfl_xor(rm[r], o));
  }
  float ps = 0.f;
  if (rA == 0) {
    const int rowb = wave * 16 + hi * 4;
#pragma unroll
    for (int r = 0; r < 4; ++r) ps += s_qm[rowb + r] ? rm[r] : 0.f;
  }
#pragma unroll
  for (int o = 32; o; o >>= 1) ps += __shfl_xor(ps, o);
  if (lane == 0) s_wsum[wave] = ps;

  __syncthreads();  // stage-19 LDS reads done before arena reuse

  float* red = (float*)&s_cb[0][0][0];  // [8 waves][2 (q,c)][512] f32 = 32 KB
  *(f4*)&red[(wave * 2 + 0) * 512 + 4 * lane] = pqA;
  *(f4*)&red[(wave * 2 + 0) * 512 + 256 + (hiHalf ? 128 : 0) + 4 * l31] = pqB;
  *(f4*)&red[(wave * 2 + 1) * 512 + 4 * lane] = pcA;
  *(f4*)&red[(wave * 2 + 1) * 512 + 256 + (hiHalf ? 128 : 0) + 4 * l31] = pcB;
  if (lane == 0) { s_cnt[wave] = cq; s_cnt[8 + wave] = cc; }
  __syncthreads();

  if (tid < DIM) {
    float sq = 0.f, sc = 0.f, nq = 0.f, nc = 0.f;
    if (tid < 256) {
#pragma unroll
      for (int w = 0; w < 8; ++w) {
        sq += red[(w * 2 + 0) * 512 + tid];
        sc += red[(w * 2 + 1) * 512 + tid];
      }
    } else {
#pragma unroll
      for (int w = 0; w < 8; ++w) {
        sq += red[(w * 2 + 0) * 512 + tid] + red[(w * 2 + 0) * 512 + tid + 128];
        sc += red[(w * 2 + 1) * 512 + tid] + red[(w * 2 + 1) * 512 + tid + 128];
      }
    }
#pragma unroll
    for (int w = 0; w < 8; ++w) { nq += s_cnt[w]; nc += s_cnt[8 + w]; }
    pooled[b * DIM + tid] = sq / fmaxf(nq, 1e-9f);
    pooled[(NB + b) * DIM + tid] = sc / fmaxf(nc, 1e-9f);
  }
  if (tid == 0) {
    float tot = 0.f;
#pragma unroll
    for (int w = 0; w < 8; ++w) tot += s_wsum[w];
    late[b] = tot;
  }
}

// ================= tail kernels: round-1/9 proven shapes =====================
__global__ __launch_bounds__(DIM)
void mlp_v1(const float* __restrict__ pooled,
            const float* __restrict__ W1, const float* __restrict__ b1,
            const float* __restrict__ W2, const float* __restrict__ b2,
            float* __restrict__ emb) {
  __shared__ float s_in[DIM];
  __shared__ float s_h[DIM];
  __shared__ float s_red[6];
  const int row = blockIdx.y * NB + blockIdx.x;
  const int d = threadIdx.x;
  s_in[d] = pooled[(size_t)row * DIM + d];
  __syncthreads();
  float acc = b1[d];
#pragma unroll 8
  for (int k = 0; k < DIM; ++k) acc = fmaf(s_in[k], W1[k * DIM + d], acc);
  s_h[d] = fmaxf(acc, 0.f);
  __syncthreads();
  float p = b2[d];
#pragma unroll 8
  for (int k = 0; k < DIM; ++k) p = fmaf(s_h[k], W2[k * DIM + d], p);
  float ss = p * p;
#pragma unroll
  for (int o = 32; o; o >>= 1) ss += __shfl_xor(ss, o);
  if ((d & 63) == 0) s_red[d >> 6] = ss;
  __syncthreads();
  float tot = 0.f;
#pragma unroll
  for (int w = 0; w < 6; ++w) tot += s_red[w];
  emb[(size_t)row * DIM + d] = p * (1.0f / fmaxf(sqrtf(tot), 1e-12f));
}

__global__ __launch_bounds__(NB)
void contrast_kernel(const float* __restrict__ emb, float* __restrict__ out0) {
  __shared__ float s_q[DIM];
  const int i = blockIdx.x;
  for (int k = threadIdx.x; k < DIM; k += NB) s_q[k] = emb[(size_t)i * DIM + k];
  __syncthreads();
  const float* ce = emb + (size_t)(NB + threadIdx.x) * DIM;
  float acc = 0.f;
#pragma unroll 8
  for (int k = 0; k < DIM; ++k) acc = fmaf(s_q[k], ce[k], acc);
  out0[(size_t)i * NB + threadIdx.x] = acc / 0.07f;
}

// ============================== launch =======================================
extern "C" void kernel_launch(void* const* d_in, const int* in_sizes, int n_in,
                              void* d_out, int out_size, void* d_ws, size_t ws_size,
                              hipStream_t stream) {
  const float* qtok = (const float*)d_in[0];
  const float* ctok = (const float*)d_in[1];
  const int*   qmm  = (const int*)d_in[2];
  const int*   cmm  = (const int*)d_in[3];
  const float* W1   = (const float*)d_in[4];
  const float* b1   = (const float*)d_in[5];
  const float* W2   = (const float*)d_in[6];
  const float* b2   = (const float*)d_in[7];

  float* out0 = (float*)d_out;            // [NB*NB]
  float* late = out0 + NB * NB;           // [NB]
  float* pooled = (float*)d_ws;           // [2*NB][DIM]
  float* emb    = pooled + 2 * NB * DIM;  // [2*NB][DIM]

  hipLaunchKernelGGL(fused2r, dim3(NB), dim3(512), 0, stream,
                     qtok, ctok, qmm, cmm, pooled, late);
  hipLaunchKernelGGL(mlp_v1, dim3(NB, 2), dim3(DIM), 0, stream,
                     pooled, W1, b1, W2, b2, emb);
  hipLaunchKernelGGL(contrast_kernel, dim3(NB), dim3(NB), 0, stream, emb, out0);
}